// Round 5
// baseline (385.212 us; speedup 1.0000x reference)
//
#include <hip/hip_runtime.h>
#include <hip/hip_bf16.h>

typedef __attribute__((ext_vector_type(8))) short short8;
typedef __attribute__((ext_vector_type(4))) float floatx4;
typedef __attribute__((ext_vector_type(4))) unsigned int uintx4;

#define WAVE_TRI 64    // 4 m-tiles of 16 per wave
#define TILE_TRI 256   // 4 waves per block
#define NTHREADS 256

// fast GELU: x * (1 - 1/(exp(2u)+1)), u = 0.79788456*(x + 0.044715 x^3)
__device__ __forceinline__ float gelu_fast(float x)
{
    float u = 0.7978845608f * x * (1.0f + 0.044715f * x * x);
    float e = __builtin_amdgcn_exp2f(2.885390082f * u);   // exp(2u)
    return x - x * __builtin_amdgcn_rcpf(e + 1.0f);
}

// Fused prep: [0,n8) fp32->bf16 cvt of f_edge (8/thread) | [n8,n8+T) dst histogram |
// [n8+T, n8+T+6144) fragment-ordered bf16 W build.
__global__ __launch_bounds__(256)
void prep(const float* __restrict__ fe_f, unsigned short* __restrict__ febf,
          const float* __restrict__ Wg, uintx4* __restrict__ wq,
          const int* __restrict__ tri, int* __restrict__ cnt, int n8, int T)
{
    int g = blockIdx.x * 256 + threadIdx.x;
    if (g < n8) {
        const float* s = fe_f + (size_t)g * 8;
        unsigned short tmp[8] __attribute__((aligned(16)));
#pragma unroll
        for (int j = 0; j < 8; ++j) {
            __hip_bfloat16 b = __float2bfloat16(s[j]);
            tmp[j] = *(unsigned short*)&b;
        }
        *(uintx4*)(febf + (size_t)g * 8) = *(const uintx4*)tmp;
    } else if (g < n8 + T) {
        int i = g - n8;
        atomicAdd(&cnt[tri[i * 3 + 2]], 1);
    } else {
        int i = g - n8 - T;
        if (i < 6144) {
            int frag = i >> 6, lane = i & 63;
            int ko = frag >> 3, nt = frag & 7;
            int col = lane & 15, quad = lane >> 4;
            unsigned short tmp[8] __attribute__((aligned(16)));
#pragma unroll
            for (int j = 0; j < 8; ++j) {
                __hip_bfloat16 b =
                    __float2bfloat16(Wg[(ko * 32 + quad * 8 + j) * 128 + nt * 16 + col]);
                tmp[j] = *(unsigned short*)&b;
            }
            wq[i] = *(const uintx4*)tmp;
        }
    }
}

// Single-block exclusive scan of cnt -> base (E elements, 8 items/thread chunks).
__global__ __launch_bounds__(1024)
void scan_single(const int* __restrict__ cnt, int* __restrict__ base, int E)
{
    __shared__ int sd[1024];
    int tid = threadIdx.x;
    int carry = 0;
    int nchunk = (E + 8191) / 8192;
    for (int c = 0; c < nchunk; ++c) {
        int g0 = c * 8192 + tid * 8;
        int v[8], s = 0;
#pragma unroll
        for (int j = 0; j < 8; ++j) {
            v[j] = (g0 + j < E) ? cnt[g0 + j] : 0;
            s += v[j];
        }
        __syncthreads();            // protect sd from previous chunk's readers
        sd[tid] = s;
        __syncthreads();
        for (int off = 1; off < 1024; off <<= 1) {
            int t = (tid >= off) ? sd[tid - off] : 0;
            __syncthreads();
            sd[tid] += t;
            __syncthreads();
        }
        int incl = sd[tid];
        int chunk_total = sd[1023];
        int run = incl - s + carry;
#pragma unroll
        for (int j = 0; j < 8; ++j) {
            if (g0 + j < E) base[g0 + j] = run;
            run += v[j];
        }
        carry += chunk_total;
    }
}

// GEMM (T x 384) @ (384 x 128): gather A (bf16 f_edge), B from LDS staged out of the
// pre-permuted wq (2 phases x 48KB). 4 m-tiles/wave -> each B fragment feeds 4 MFMAs.
// Epilogue: bias+GELU, CSR slot via atomicAdd(&base[dst],1), bf16 row at ht[slot].
__global__ __launch_bounds__(NTHREADS, 2)
void tri_gemm(const unsigned short* __restrict__ fe,   // bf16 bits, E*128
              const uintx4* __restrict__ wq,           // fragment-ordered bf16 W
              const float* __restrict__ bias,          // fp32, 128
              const int* __restrict__ tri,             // T*3 int32
              int* __restrict__ base,                  // CSR cursors (mutated!)
              unsigned short* __restrict__ ht,         // bf16 bits, T*128 (CSR order)
              int T)
{
    __shared__ uintx4 ldsW[3072];   // 48 KB per phase

    const int tid  = threadIdx.x;
    const int wv   = tid >> 6;
    const int lane = tid & 63;
    const int col  = lane & 15;
    const int quad = lane >> 4;
    const int tb   = blockIdx.x * TILE_TRI + wv * WAVE_TRI;

    unsigned int offs[4][3];
#pragma unroll
    for (int mi = 0; mi < 4; ++mi) {
        int t  = tb + mi * 16 + col;
        int tc = t < T ? t : 0;
        offs[mi][0] = (unsigned)tri[tc * 3 + 0] * 256u;
        offs[mi][1] = (unsigned)tri[tc * 3 + 1] * 256u;
        offs[mi][2] = (unsigned)tri[tc * 3 + 2] * 256u;
    }
    const char* feb = (const char*)fe;

    floatx4 acc[4][8];
#pragma unroll
    for (int mi = 0; mi < 4; ++mi)
#pragma unroll
        for (int nt = 0; nt < 8; ++nt) acc[mi][nt] = (floatx4)0.0f;

#pragma unroll 1
    for (int p = 0; p < 2; ++p) {
        if (p) __syncthreads();   // all waves done reading phase-0 LDS
        // Stage 48KB of pre-permuted W: coalesced 16B loads + conflict-free b128 writes
#pragma unroll
        for (int i = 0; i < 12; ++i) {
            int idx = i * 256 + tid;
            ldsW[idx] = wq[p * 3072 + idx];
        }
        __syncthreads();

#pragma unroll
        for (int kol = 0; kol < 6; ++kol) {
            int ko  = p * 6 + kol;
            int sgi = ko >> 2;
            int o   = ((ko & 3) << 6) + (quad << 4);
            short8 a[4];
#pragma unroll
            for (int mi = 0; mi < 4; ++mi)
                a[mi] = *(const short8*)(feb + offs[mi][sgi] + o);
#pragma unroll
            for (int nt = 0; nt < 8; ++nt) {
                short8 bf = *(const short8*)&ldsW[(kol * 8 + nt) * 64 + lane];
#pragma unroll
                for (int mi = 0; mi < 4; ++mi)
                    acc[mi][nt] = __builtin_amdgcn_mfma_f32_16x16x32_bf16(
                        a[mi], bf, acc[mi][nt], 0, 0, 0);
            }
        }
    }

    float bv[8];
#pragma unroll
    for (int nt = 0; nt < 8; ++nt) bv[nt] = bias[nt * 16 + col];

#pragma unroll
    for (int mi = 0; mi < 4; ++mi) {
#pragma unroll
        for (int r = 0; r < 4; ++r) {
            int t = tb + mi * 16 + quad * 4 + r;   // D row = quad*4 + reg
            if (t < T) {
                int p2 = 0;
                if (col == 0) p2 = atomicAdd(&base[tri[t * 3 + 2]], 1);
                p2 = __shfl(p2, lane & 48);        // broadcast from quad's lane 0
                unsigned short pk[8] __attribute__((aligned(16)));
#pragma unroll
                for (int nt = 0; nt < 8; ++nt) {
                    float h = gelu_fast(acc[mi][nt][r] + bv[nt]);
                    __hip_bfloat16 hb = __float2bfloat16(h);
                    pk[nt] = *(unsigned short*)&hb;
                }
                *(uintx4*)(ht + (size_t)p2 * 128 + col * 8) = *(const uintx4*)pk;
            }
        }
    }
}

// Per-edge mean + LayerNorm over contiguous CSR runs (base[d]=end, start=end-cnt).
__global__ __launch_bounds__(256)
void mean_ln(const unsigned short* __restrict__ ht,
             const int* __restrict__ base, const int* __restrict__ cnt,
             const float* __restrict__ gamma, const float* __restrict__ beta,
             float* __restrict__ out, int E)
{
    int lane = threadIdx.x & 63;
    int row  = blockIdx.x * 4 + (threadIdx.x >> 6);
    if (row >= E) return;
    int col = lane & 15, q = lane >> 4;
    const char* htb = (const char*)ht;
    int boff = (col << 4) + (q << 2);   // byte offset within 256B row

    int e = base[row];
    int c = cnt[row];
    int s = e - c;
    float x0 = 0.0f, x1 = 0.0f;
    for (int i = s; i < e; ++i) {
        unsigned int w = *(const unsigned int*)(htb + (size_t)i * 256 + boff);
        x0 += __uint_as_float(w << 16);          // logical col j0 = 32q+col
        x1 += __uint_as_float(w & 0xffff0000u);  // logical col j1 = j0+16
    }
    float inv = 1.0f / fmaxf((float)c, 1.0f);
    float m0 = x0 * inv, m1 = x1 * inv;
    float sm = m0 + m1;
#pragma unroll
    for (int o = 32; o > 0; o >>= 1) sm += __shfl_xor(sm, o);
    float mu = sm * (1.0f / 128.0f);
    float d0 = m0 - mu, d1 = m1 - mu;
    float v = d0 * d0 + d1 * d1;
#pragma unroll
    for (int o = 32; o > 0; o >>= 1) v += __shfl_xor(v, o);
    float rstd = rsqrtf(v * (1.0f / 128.0f) + 1e-5f);
    int j0 = q * 32 + col, j1 = j0 + 16;
    out[(size_t)row * 128 + j0] = d0 * rstd * gamma[j0] + beta[j0];
    out[(size_t)row * 128 + j1] = d1 * rstd * gamma[j1] + beta[j1];
}

extern "C" void kernel_launch(void* const* d_in, const int* in_sizes, int n_in,
                              void* d_out, int out_size, void* d_ws, size_t ws_size,
                              hipStream_t stream)
{
    const float* fe_f  = (const float*)d_in[0];
    const float* Wg    = (const float*)d_in[1];
    const float* bias  = (const float*)d_in[2];
    const float* gamma = (const float*)d_in[3];
    const float* beta  = (const float*)d_in[4];
    const int*   tri   = (const int*)d_in[5];

    int E = in_sizes[0] / 128;
    int T = in_sizes[5] / 3;

    // ws: ht (T*128 bf16) | febf (E*128 bf16) | wq (96KB) | cnt (E i32) | base (E i32)
    unsigned short* ht   = (unsigned short*)d_ws;
    unsigned short* febf = ht + (size_t)T * 128;
    uintx4* wq = (uintx4*)(febf + (size_t)E * 128);
    int* cnt  = (int*)((char*)wq + 6144 * 16);
    int* base = cnt + E;

    hipMemsetAsync(cnt, 0, (size_t)E * sizeof(int), stream);

    int n8 = E * 128 / 8;
    int total = n8 + T + 6144;
    prep<<<(total + 255) / 256, 256, 0, stream>>>(fe_f, febf, Wg, wq, tri, cnt, n8, T);

    scan_single<<<1, 1024, 0, stream>>>(cnt, base, E);

    tri_gemm<<<(T + TILE_TRI - 1) / TILE_TRI, NTHREADS, 0, stream>>>(
        febf, wq, bias, tri, base, ht, T);

    mean_ln<<<(E + 3) / 4, 256, 0, stream>>>(ht, base, cnt, gamma, beta,
                                             (float*)d_out, E);
}

// Round 6
// 255.340 us; speedup vs baseline: 1.5086x; 1.5086x over previous
//
#include <hip/hip_runtime.h>
#include <hip/hip_bf16.h>

typedef __attribute__((ext_vector_type(8))) short short8;
typedef __attribute__((ext_vector_type(4))) float floatx4;
typedef __attribute__((ext_vector_type(4))) unsigned int uintx4;

// fast GELU: x * (1 - 1/(exp(2u)+1)), u = 0.79788456*(x + 0.044715 x^3)
__device__ __forceinline__ float gelu_fast(float x)
{
    float u = 0.7978845608f * x * (1.0f + 0.044715f * x * x);
    float e = __builtin_amdgcn_exp2f(2.885390082f * u);   // exp(2u)
    return x - x * __builtin_amdgcn_rcpf(e + 1.0f);
}

// prep: [0,T): linked-list records keyed by dst=tri[:,2]; [T,T+6144): fragment-
// ordered bf16 W (frag f=ko*8+nt, lane l: 8 elems W[ko*32+quad*8+j][nt*16+col]).
__global__ __launch_bounds__(256)
void prep(const float* __restrict__ Wg, uintx4* __restrict__ wq,
          const int* __restrict__ tri, int* __restrict__ head,
          int4* __restrict__ rec, int T)
{
    int g = blockIdx.x * 256 + threadIdx.x;
    if (g < T) {
        int i0 = tri[g * 3 + 0];
        int i1 = tri[g * 3 + 1];
        int i2 = tri[g * 3 + 2];
        int w = atomicExch(&head[i2], g);
        rec[g] = make_int4(w, i0, i1, i2);
    } else {
        int i = g - T;
        if (i < 6144) {
            int frag = i >> 6, lane = i & 63;
            int ko = frag >> 3, nt = frag & 7;
            int col = lane & 15, quad = lane >> 4;
            unsigned short tmp[8] __attribute__((aligned(16)));
#pragma unroll
            for (int j = 0; j < 8; ++j) {
                __hip_bfloat16 b =
                    __float2bfloat16(Wg[(ko * 32 + quad * 8 + j) * 128 + nt * 16 + col]);
                tmp[j] = *(unsigned short*)&b;
            }
            wq[i] = *(const uintx4*)tmp;
        }
    }
}

// Dense GEMM: G_r = f_edge (E x 128 fp32, cvt to bf16 in-regs) @ W_r (128x128),
// r = 0,1,2 as 3 phases with 32KB LDS of pre-permuted B each. Output bf16 in
// permuted C-layout (row i: physical elem col*8+nt = logical col nt*16+col).
__global__ __launch_bounds__(512, 2)
void edge_gemm(const float* __restrict__ fe_f, const uintx4* __restrict__ wq,
               unsigned short* __restrict__ G, int E)
{
    __shared__ uintx4 ldsW[2048];   // 32 KB: 4 ko x 8 nt fragment blocks

    const int tid  = threadIdx.x;
    const int wv   = tid >> 6;
    const int lane = tid & 63;
    const int col  = lane & 15;
    const int quad = lane >> 4;
    const int ntiles = (E + 15) >> 4;

#pragma unroll 1
    for (int r = 0; r < 3; ++r) {
        __syncthreads();
        for (int i = tid; i < 2048; i += 512) ldsW[i] = wq[r * 2048 + i];
        __syncthreads();
        unsigned short* Gr = G + (size_t)r * E * 128;

#pragma unroll 1
        for (int tile = blockIdx.x * 8 + wv; tile < ntiles; tile += gridDim.x * 8) {
            int row_a = tile * 16 + col;
            if (row_a >= E) row_a = E - 1;
            const float* arow = fe_f + (size_t)row_a * 128 + quad * 8;

            floatx4 acc[8];
#pragma unroll
            for (int nt = 0; nt < 8; ++nt) acc[nt] = (floatx4)0.0f;

#pragma unroll
            for (int ko = 0; ko < 4; ++ko) {
                float a0[8];
                *(floatx4*)&a0[0] = *(const floatx4*)(arow + ko * 32);
                *(floatx4*)&a0[4] = *(const floatx4*)(arow + ko * 32 + 4);
                short8 a;
#pragma unroll
                for (int j = 0; j < 8; ++j) {
                    __hip_bfloat16 b = __float2bfloat16(a0[j]);
                    a[j] = *(short*)&b;
                }
#pragma unroll
                for (int nt = 0; nt < 8; ++nt) {
                    short8 bf = *(const short8*)&ldsW[(ko * 8 + nt) * 64 + lane];
                    acc[nt] = __builtin_amdgcn_mfma_f32_16x16x32_bf16(a, bf, acc[nt], 0, 0, 0);
                }
            }

#pragma unroll
            for (int rr = 0; rr < 4; ++rr) {
                int row = tile * 16 + quad * 4 + rr;   // D row = quad*4 + reg
                if (row < E) {
                    unsigned short pk[8] __attribute__((aligned(16)));
#pragma unroll
                    for (int nt = 0; nt < 8; ++nt) {
                        __hip_bfloat16 hb = __float2bfloat16(acc[nt][rr]);
                        pk[nt] = *(unsigned short*)&hb;
                    }
                    *(uintx4*)(Gr + (size_t)row * 128 + col * 8) = *(const uintx4*)pk;
                }
            }
        }
    }
}

// Per-edge fused gather + GELU + mean + LayerNorm. One wave per edge row; walk
// the triangle list (rec = {next,i0,i1,i2}, one 16B uniform load per step);
// per triangle 3 independent coalesced 256B row-gathers from G0/G1/G2.
// Lane (col,q) covers logical cols j0=32q+col, j1=j0+16 (permuted layout).
__global__ __launch_bounds__(256)
void mean_ln_g(const unsigned short* __restrict__ G, const int* __restrict__ head,
               const int4* __restrict__ rec, const float* __restrict__ bias,
               const float* __restrict__ gamma, const float* __restrict__ beta,
               float* __restrict__ out, int E)
{
    int lane = threadIdx.x & 63;
    int row  = blockIdx.x * 4 + (threadIdx.x >> 6);
    if (row >= E) return;
    int col = lane & 15, q = lane >> 4;
    int boff = (col << 4) + (q << 2);   // byte offset within 256B row
    const char* g0 = (const char*)G;
    const char* g1 = g0 + (size_t)E * 256;
    const char* g2 = g1 + (size_t)E * 256;
    int j0 = q * 32 + col, j1 = j0 + 16;
    float bv0 = bias[j0], bv1 = bias[j1];

    float x0 = 0.0f, x1 = 0.0f;
    int c = 0;
    int t = head[row];
    while (t >= 0) {
        int4 rc = rec[t];
        unsigned int w0 = *(const unsigned int*)(g0 + (size_t)rc.y * 256 + boff);
        unsigned int w1 = *(const unsigned int*)(g1 + (size_t)rc.z * 256 + boff);
        unsigned int w2 = *(const unsigned int*)(g2 + (size_t)rc.w * 256 + boff);
        float s0 = __uint_as_float(w0 << 16) + __uint_as_float(w1 << 16)
                 + __uint_as_float(w2 << 16) + bv0;
        float s1 = __uint_as_float(w0 & 0xffff0000u) + __uint_as_float(w1 & 0xffff0000u)
                 + __uint_as_float(w2 & 0xffff0000u) + bv1;
        x0 += gelu_fast(s0);
        x1 += gelu_fast(s1);
        ++c;
        t = rc.x;
    }

    float inv = 1.0f / fmaxf((float)c, 1.0f);
    float m0 = x0 * inv, m1 = x1 * inv;
    float sm = m0 + m1;
#pragma unroll
    for (int o = 32; o > 0; o >>= 1) sm += __shfl_xor(sm, o);
    float mu = sm * (1.0f / 128.0f);
    float d0 = m0 - mu, d1 = m1 - mu;
    float v = d0 * d0 + d1 * d1;
#pragma unroll
    for (int o = 32; o > 0; o >>= 1) v += __shfl_xor(v, o);
    float rstd = rsqrtf(v * (1.0f / 128.0f) + 1e-5f);
    out[(size_t)row * 128 + j0] = d0 * rstd * gamma[j0] + beta[j0];
    out[(size_t)row * 128 + j1] = d1 * rstd * gamma[j1] + beta[j1];
}

extern "C" void kernel_launch(void* const* d_in, const int* in_sizes, int n_in,
                              void* d_out, int out_size, void* d_ws, size_t ws_size,
                              hipStream_t stream)
{
    const float* fe_f  = (const float*)d_in[0];
    const float* Wg    = (const float*)d_in[1];
    const float* bias  = (const float*)d_in[2];
    const float* gamma = (const float*)d_in[3];
    const float* beta  = (const float*)d_in[4];
    const int*   tri   = (const int*)d_in[5];

    int E = in_sizes[0] / 128;
    int T = in_sizes[5] / 3;

    // ws: G (3*E*128 bf16) | rec (T int4) | wq (96KB) | head (E i32)
    unsigned short* G = (unsigned short*)d_ws;
    int4* rec = (int4*)(G + (size_t)3 * E * 128);
    uintx4* wq = (uintx4*)(rec + T);
    int* head = (int*)(wq + 6144);

    hipMemsetAsync(head, 0xFF, (size_t)E * sizeof(int), stream);   // head = -1

    int total = T + 6144;
    prep<<<(total + 255) / 256, 256, 0, stream>>>(Wg, wq, tri, head, rec, T);

    edge_gemm<<<512, 512, 0, stream>>>(fe_f, wq, G, E);

    mean_ln_g<<<(E + 3) / 4, 256, 0, stream>>>(G, head, rec, bias, gamma, beta,
                                               (float*)d_out, E);
}